// Round 6
// baseline (116.538 us; speedup 1.0000x reference)
//
#include <hip/hip_runtime.h>
#include <math.h>

#define BB 8
#define LL 32768
#define DD 64
#define GH 16
#define TC 128
#define NC (LL / TC)   /* 256 chunks */
#define BD (BB * DD)   /* 512 chains */
#define WIN 16
#define PAD 8

typedef float f32x2 __attribute__((ext_vector_type(2)));

__device__ __forceinline__ float sig_(float z) { return 1.0f / (1.0f + expf(-z)); }

__device__ __forceinline__ float raw_gate(float xv, const float* w1, const float* bb1,
                                          const float* w2, float bb2) {
    float h = bb2;
#pragma unroll
    for (int i = 0; i < GH; i++) {
        const float z = xv * w1[i] + bb1[i];
        h += (z * sig_(z)) * w2[i];           // silu
    }
    return sig_(h);
}

// ---------------- Kernel 1: smoothed gate gamma(b,t) ----------------
__global__ __launch_bounds__(256) void gate_kernel(
        const float* __restrict__ x,
        const float* __restrict__ W1, const float* __restrict__ b1,
        const float* __restrict__ W2, const float* __restrict__ b2,
        float* __restrict__ gw) {
    __shared__ float sraw[256 + WIN];  // raw gate for t0-8 .. t0+263
    const int tilesPerB = LL / 256;
    const int b  = blockIdx.x / tilesPerB;
    const int t0 = (blockIdx.x % tilesPerB) * 256;

    float w1[GH], bb1[GH], w2[GH];
#pragma unroll
    for (int i = 0; i < GH; i++) { w1[i] = W1[i]; bb1[i] = b1[i]; w2[i] = W2[i]; }
    const float bb2 = b2[0];

    for (int j = threadIdx.x; j < 256 + WIN; j += 256) {
        int idx = t0 - PAD + j;
        if (idx < 0)    idx = -idx;               // reflect (no edge repeat)
        if (idx >= LL)  idx = 2 * LL - 2 - idx;
        sraw[j] = raw_gate(x[b * LL + idx], w1, bb1, w2, bb2);
    }
    __syncthreads();

    float acc = 0.0f;
#pragma unroll
    for (int k = 0; k < WIN; k++) acc += sraw[threadIdx.x + k];
    gw[b * LL + t0 + threadIdx.x] = acc * (1.0f / WIN);
}

// ---------------- per-thread channel params ----------------
__device__ __forceinline__ void chan_params(const float* omega, const float* raw_alpha,
                                            int d, float& ar, float& ai) {
    const float alpha = -log1pf(expf(raw_alpha[d]));  // -softplus
    const float r = expf(alpha);
    ar = r * cosf(omega[d]);
    ai = r * sinf(omega[d]);
}

// ---------------- Kernel 2: per-chunk composite (P, S) ----------------
__global__ __launch_bounds__(256) void chunk_reduce_kernel(
        const float* __restrict__ x, const float* __restrict__ gw,
        const float* __restrict__ omega, const float* __restrict__ raw_alpha,
        const float* __restrict__ b_real, const float* __restrict__ b_imag,
        float4* __restrict__ ps) {
    const int tid = blockIdx.x * blockDim.x + threadIdx.x;
    const int d = tid & (DD - 1);
    const int u = tid >> 6;          // (b, c), wave-uniform
    const int b = u / NC;
    const int c = u % NC;

    float ar, ai;
    chan_params(omega, raw_alpha, d, ar, ai);
    const float br = b_real[d], bi = b_imag[d];

    float Pr = 1.0f, Pi = 0.0f, Sr = 0.0f, Si = 0.0f;
    const float4* xb4 = (const float4*)(x  + b * LL + c * TC);
    const float4* gb4 = (const float4*)(gw + b * LL + c * TC);
#pragma unroll 2
    for (int q = 0; q < TC / 4; q++) {
        const float4 g4 = gb4[q];
        const float4 x4 = xb4[q];
        const float gs[4] = {g4.x, g4.y, g4.z, g4.w};
        const float xs[4] = {x4.x, x4.y, x4.z, x4.w};
#pragma unroll
        for (int j = 0; j < 4; j++) {
            const float cr = gs[j] * ar, ci = gs[j] * ai;
            const float nPr = cr * Pr - ci * Pi;
            const float nPi = cr * Pi + ci * Pr;
            const float nSr = cr * Sr - ci * Si + br * xs[j];
            const float nSi = cr * Si + ci * Sr + bi * xs[j];
            Pr = nPr; Pi = nPi; Sr = nSr; Si = nSi;
        }
    }
    ps[(b * DD + d) * NC + c] = make_float4(Pr, Pi, Sr, Si);
}

// ---------------- Kernel 3: carry scan (one wave per (b,d)) ----------------
__global__ __launch_bounds__(256) void carry_scan_kernel(
        const float4* __restrict__ ps, float2* __restrict__ hin) {
    const int w    = blockIdx.x * (blockDim.x >> 6) + (threadIdx.x >> 6);  // bd chain
    const int lane = threadIdx.x & 63;
    const int c0   = lane * 4;                                             // 4 chunks/lane

    float4 v[4];
#pragma unroll
    for (int j = 0; j < 4; j++) v[j] = ps[w * NC + c0 + j];

    // compose the 4 chunks of this lane (apply in time order)
    float Pr = 1.0f, Pi = 0.0f, Sr = 0.0f, Si = 0.0f;
#pragma unroll
    for (int j = 0; j < 4; j++) {
        const float pr = v[j].x, pi = v[j].y, sr = v[j].z, si = v[j].w;
        const float nPr = pr * Pr - pi * Pi;
        const float nPi = pr * Pi + pi * Pr;
        const float nSr = pr * Sr - pi * Si + sr;
        const float nSi = pr * Si + pi * Sr + si;
        Pr = nPr; Pi = nPi; Sr = nSr; Si = nSi;
    }

    // Kogge-Stone inclusive scan across 64 lanes; cur∘prev: P=Pc*Pp, S=Pc*Sp+Sc
#pragma unroll
    for (int off = 1; off < 64; off <<= 1) {
        const float pPr = __shfl_up(Pr, off, 64);
        const float pPi = __shfl_up(Pi, off, 64);
        const float pSr = __shfl_up(Sr, off, 64);
        const float pSi = __shfl_up(Si, off, 64);
        if (lane >= off) {
            const float nPr = Pr * pPr - Pi * pPi;
            const float nPi = Pr * pPi + Pi * pPr;
            const float nSr = Pr * pSr - Pi * pSi + Sr;
            const float nSi = Pr * pSi + Pi * pSr + Si;
            Pr = nPr; Pi = nPi; Sr = nSr; Si = nSi;
        }
    }

    // incoming h for this lane's group = exclusive-scan S (h0 = 0)
    float hr = __shfl_up(Sr, 1, 64);
    float hi = __shfl_up(Si, 1, 64);
    if (lane == 0) { hr = 0.0f; hi = 0.0f; }

#pragma unroll
    for (int j = 0; j < 4; j++) {
        hin[(c0 + j) * BD + w] = make_float2(hr, hi);
        const float pr = v[j].x, pi = v[j].y, sr = v[j].z, si = v[j].w;
        const float nhr = pr * hr - pi * hi + sr;
        const float nhi = pr * hi + pi * hr + si;
        hr = nhr; hi = nhi;
    }
}

// ---- Kernel 4: expand — replay chunk from carry, stream output ----
// CPLX=true: interleaved (re,im) f32x2 at [(b*L+t)*D+d]; CPLX=false: real part only.
template <bool CPLX>
__global__ __launch_bounds__(256) void expand_kernel(
        const float* __restrict__ x, const float* __restrict__ gw,
        const float* __restrict__ omega, const float* __restrict__ raw_alpha,
        const float* __restrict__ b_real, const float* __restrict__ b_imag,
        const float2* __restrict__ hin, float* __restrict__ out) {
    const int tid = blockIdx.x * blockDim.x + threadIdx.x;
    const int d = tid & (DD - 1);
    const int u = tid >> 6;
    const int b = u / NC;
    const int c = u % NC;

    float ar, ai;
    chan_params(omega, raw_alpha, d, ar, ai);
    const float br = b_real[d], bi = b_imag[d];

    const float2 h0 = hin[c * BD + (b * DD + d)];
    float hr = h0.x, hi = h0.y;

    const float4* xb4 = (const float4*)(x  + b * LL + c * TC);
    const float4* gb4 = (const float4*)(gw + b * LL + c * TC);
    const size_t base = (size_t)(b * LL + c * TC) * DD + d;

#pragma unroll 2
    for (int q = 0; q < TC / 4; q++) {
        const float4 g4 = gb4[q];
        const float4 x4 = xb4[q];
        const float gs[4] = {g4.x, g4.y, g4.z, g4.w};
        const float xs[4] = {x4.x, x4.y, x4.z, x4.w};
#pragma unroll
        for (int j = 0; j < 4; j++) {
            const float cr = gs[j] * ar, ci = gs[j] * ai;
            const float nhr = cr * hr - ci * hi + br * xs[j];
            const float nhi = cr * hi + ci * hr + bi * xs[j];
            hr = nhr; hi = nhi;
            const size_t e = base + (size_t)(q * 4 + j) * DD;
            if constexpr (CPLX) {
                f32x2 val; val.x = hr; val.y = hi;
                __builtin_nontemporal_store(val, (f32x2*)out + e);
            } else {
                __builtin_nontemporal_store(hr, out + e);
            }
        }
    }
}

// ---------------- Zero-scratch fallback: serial scan, 1 block per batch ----------------
template <bool CPLX>
__global__ __launch_bounds__(64) void fallback_kernel(
        const float* __restrict__ x,
        const float* __restrict__ omega, const float* __restrict__ raw_alpha,
        const float* __restrict__ b_real, const float* __restrict__ b_imag,
        const float* __restrict__ W1, const float* __restrict__ b1,
        const float* __restrict__ W2, const float* __restrict__ b2,
        float* __restrict__ out) {
    const int b = blockIdx.x;        // 8 blocks
    const int d = threadIdx.x;       // 64 chains per block

    __shared__ float xtile[64];
    __shared__ float sraw[64 + WIN]; // raw gate t0-8 .. t0+71
    __shared__ float gsm[64];        // smoothed gate for tile

    float w1[GH], bb1[GH], w2[GH];
#pragma unroll
    for (int i = 0; i < GH; i++) { w1[i] = W1[i]; bb1[i] = b1[i]; w2[i] = W2[i]; }
    const float bb2 = b2[0];

    float ar, ai;
    chan_params(omega, raw_alpha, d, ar, ai);
    const float br = b_real[d], bi = b_imag[d];

    float hr = 0.0f, hi = 0.0f;
    for (int t0 = 0; t0 < LL; t0 += 64) {
        __syncthreads();             // previous tile's LDS reads done
        for (int j = threadIdx.x; j < 64 + WIN; j += 64) {
            int idx = t0 - PAD + j;
            if (idx < 0)   idx = -idx;
            if (idx >= LL) idx = 2 * LL - 2 - idx;
            sraw[j] = raw_gate(x[b * LL + idx], w1, bb1, w2, bb2);
        }
        xtile[threadIdx.x] = x[b * LL + t0 + threadIdx.x];
        __syncthreads();
        float acc = 0.0f;
#pragma unroll
        for (int k = 0; k < WIN; k++) acc += sraw[threadIdx.x + k];
        gsm[threadIdx.x] = acc * (1.0f / WIN);
        __syncthreads();
        for (int tt = 0; tt < 64; tt++) {
            const float g  = gsm[tt];
            const float xv = xtile[tt];
            const float cr = g * ar, ci = g * ai;
            const float nhr = cr * hr - ci * hi + br * xv;
            const float nhi = cr * hi + ci * hr + bi * xv;
            hr = nhr; hi = nhi;
            const size_t e = (size_t)(b * LL + t0 + tt) * DD + d;
            if constexpr (CPLX) {
                f32x2 val; val.x = hr; val.y = hi;
                ((f32x2*)out)[e] = val;
            } else {
                out[e] = hr;
            }
        }
    }
}

extern "C" void kernel_launch(void* const* d_in, const int* in_sizes, int n_in,
                              void* d_out, int out_size, void* d_ws, size_t ws_size,
                              hipStream_t stream) {
    const float* x         = (const float*)d_in[0];
    const float* omega     = (const float*)d_in[1];
    const float* raw_alpha = (const float*)d_in[2];
    const float* b_real    = (const float*)d_in[3];
    const float* b_imag    = (const float*)d_in[4];
    const float* W1        = (const float*)d_in[5];
    const float* b1        = (const float*)d_in[6];
    const float* W2        = (const float*)d_in[7];
    const float* b2        = (const float*)d_in[8];

    float* out = (float*)d_out;

    // Output layout: harness passes out_size in ELEMENTS of the output dtype view.
    // 2*B*L*D  -> complex64 viewed as interleaved float pairs (write re,im).
    // otherwise -> float32 real part only (complex64 .astype(float32) drops imag).
    const long long NOUT = (long long)BB * LL * DD;
    const bool cplx = ((long long)out_size == 2 * NOUT);

    // scratch layout: gw (1 MiB) | ps (2 MiB) | hin (1 MiB)
    const size_t WSNEED = (size_t)BB * LL * 4 + (size_t)BD * NC * 16 + (size_t)BD * NC * 8;

    if (ws_size >= WSNEED) {
        float*  ws  = (float*)d_ws;
        float*  gw  = ws;
        float4* ps  = (float4*)(ws + BB * LL);
        float2* hin = (float2*)(ws + BB * LL + BD * NC * 4);

        gate_kernel<<<BB * (LL / 256), 256, 0, stream>>>(x, W1, b1, W2, b2, gw);
        chunk_reduce_kernel<<<(BD * NC) / 256, 256, 0, stream>>>(x, gw, omega, raw_alpha,
                                                                 b_real, b_imag, ps);
        carry_scan_kernel<<<BD / 4, 256, 0, stream>>>(ps, hin);
        if (cplx) {
            expand_kernel<true><<<(BD * NC) / 256, 256, 0, stream>>>(
                x, gw, omega, raw_alpha, b_real, b_imag, hin, out);
        } else {
            expand_kernel<false><<<(BD * NC) / 256, 256, 0, stream>>>(
                x, gw, omega, raw_alpha, b_real, b_imag, hin, out);
        }
    } else {
        if (cplx) {
            fallback_kernel<true><<<BB, 64, 0, stream>>>(
                x, omega, raw_alpha, b_real, b_imag, W1, b1, W2, b2, out);
        } else {
            fallback_kernel<false><<<BB, 64, 0, stream>>>(
                x, omega, raw_alpha, b_real, b_imag, W1, b1, W2, b2, out);
        }
    }
}